// Round 4
// baseline (146.271 us; speedup 1.0000x reference)
//
#include <hip/hip_runtime.h>
#include <stdint.h>

// TargetTokenEncoder: histogram-stats -> MLP(14->256 GELU ->256) fused.
// R4: fully wave-independent, ZERO-LDS design. Each wave owns 32 rows:
// in-wave histogram (2 lanes/row, packed 6-bit counters), stats distributed
// by ds_bpermute shuffles, GEMM1 -> GELU -> h kept in 64 VGPRs (bf16-packed,
// rearranged to GEMM2 B-frag layout via one shfl_xor(32) per chunk), GEMM2
// streams w2f fragments from L2. No __syncthreads, no LDS bank conflicts.

#define SSUP 128
#define DD   256

typedef __attribute__((ext_vector_type(8)))  short bf16x8;   // 8 bf16 = 4 VGPRs
typedef __attribute__((ext_vector_type(16))) float f32x16;   // C/D for 32x32 MFMA

__device__ __forceinline__ unsigned f2bf_u(float f) {
    union { float f; unsigned u; } v; v.f = f;
    return (v.u + 0x7FFFu + ((v.u >> 16) & 1u)) >> 16;   // RNE, no NaNs here
}
__device__ __forceinline__ unsigned pk2(float a, float b) {
    return f2bf_u(a) | (f2bf_u(b) << 16);
}

// tanh-form GELU, tightened: gelu(x) = x / (1 + exp(-2z)), z = x(a + b x^2).
// Saturates correctly (exp->inf => 0; exp->0 => x).
__device__ __forceinline__ float gelu_f(float x) {
    float t = x * x;
    float u = __builtin_fmaf(t, 0.035677408136f, 0.7978845608028654f);
    float e = __expf(x * u * -2.0f);
    return x * __builtin_amdgcn_rcpf(1.0f + e);
}

// Fragment-major weights (A-operand: i = n = 32nt + (l&31), k = (l>>5)*8+j):
//   w2f[((s*8 + nt)*64 + l)*8 + j] = bf16(w2[(s*16 + (l>>5)*8 + j)*256 + n])
//   w1f[(nt*64 + l)*8 + j]         = bf16(w1[((l>>5)*8+j)*256 + n]), pad k>=14
__global__ void prep_kernel(const float* __restrict__ w1,
                            const float* __restrict__ w2,
                            unsigned short* __restrict__ w1f,
                            unsigned short* __restrict__ w2f) {
    int tid = blockIdx.x * 256 + threadIdx.x;
    if (tid < 8192) {                       // w2f: one thread per (s,nt,lane)
        int l  = tid & 63;
        int nt = (tid >> 6) & 7;
        int s  = tid >> 9;
        int n  = nt * 32 + (l & 31);
        int k0 = s * 16 + (l >> 5) * 8;
        unsigned pk[4];
        #pragma unroll
        for (int h = 0; h < 4; ++h)
            pk[h] = pk2(w2[(size_t)(k0 + 2*h) * DD + n],
                        w2[(size_t)(k0 + 2*h + 1) * DD + n]);
        *(uint4*)&w2f[(size_t)tid * 8] = make_uint4(pk[0], pk[1], pk[2], pk[3]);
    } else if (tid < 8704) {                // w1f
        int idx = tid - 8192;
        int l   = idx & 63;
        int nt  = idx >> 6;
        int n   = nt * 32 + (l & 31);
        int kk0 = (l >> 5) * 8;
        unsigned pk[4];
        #pragma unroll
        for (int h = 0; h < 4; ++h) {
            int ka = kk0 + 2*h, kb = kk0 + 2*h + 1;
            float fa = (ka < 14) ? w1[(size_t)ka * DD + n] : 0.0f;
            float fb = (kb < 14) ? w1[(size_t)kb * DD + n] : 0.0f;
            pk[h] = pk2(fa, fb);
        }
        *(uint4*)&w1f[(size_t)idx * 8] = make_uint4(pk[0], pk[1], pk[2], pk[3]);
    }
}

__global__ __launch_bounds__(256, 4)
void encoder_kernel(const int* __restrict__ y,
                    const float* __restrict__ b1,
                    const float* __restrict__ b2,
                    const unsigned short* __restrict__ w1f,
                    const unsigned short* __restrict__ w2f,
                    float* __restrict__ out) {
    const int tid  = threadIdx.x;
    const int lane = tid & 63;
    const int wid  = tid >> 6;
    const int l31  = lane & 31;
    const int lh   = lane >> 5;
    const int rbase = blockIdx.x * 128 + wid * 32;   // 32 rows per wave

    // ---------------- Phase 1: in-wave histogram (2 lanes/row) ----------------
    // Each lane: 64 labels in two 32-label groups, 10 counters 6-bit-packed.
    const int hrow = lane >> 1;
    const int hq   = lane & 1;
    const int4* yp = (const int4*)(y + (size_t)(rbase + hrow) * SSUP);
    unsigned long long pka = 0ull, pkb = 0ull;
    #pragma unroll
    for (int i = 0; i < 8; ++i) {
        int4 v = yp[2 * i + hq];
        pka += 1ull << (6 * v.x);
        pka += 1ull << (6 * v.y);
        pka += 1ull << (6 * v.z);
        pka += 1ull << (6 * v.w);
    }
    #pragma unroll
    for (int i = 8; i < 16; ++i) {
        int4 v = yp[2 * i + hq];
        pkb += 1ull << (6 * v.x);
        pkb += 1ull << (6 * v.y);
        pkb += 1ull << (6 * v.z);
        pkb += 1ull << (6 * v.w);
    }
    float p[10]; float ent = 0.f, pmax = 0.f, nnz = 0.f;
    #pragma unroll
    for (int c = 0; c < 10; ++c) {
        int cc = (int)((pka >> (6 * c)) & 63ull) + (int)((pkb >> (6 * c)) & 63ull);
        cc += __shfl_xor(cc, 1);                  // pair-reduce: both lanes get total
        float pc = (float)cc * 0.0078125f;        // total is always 128
        p[c] = pc;
        nnz += (cc > 0) ? 1.0f : 0.0f;
        ent -= pc * __logf(pc + 1e-6f);
        pmax = fmaxf(pmax, pc);
    }
    // Pack stats as bf16: even lane of pair holds k0..7, odd holds k8..15.
    unsigned sp0 = hq ? pk2(p[8], p[9])     : pk2(p[0], p[1]);
    unsigned sp1 = hq ? pk2(nnz, ent)       : pk2(p[2], p[3]);
    unsigned sp2 = hq ? pk2(128.0f, pmax)   : pk2(p[4], p[5]);
    unsigned sp3 = hq ? 0u                  : pk2(p[6], p[7]);
    // Redistribute to B-frag layout: lane (m=l31, lh) reads from lane 2*m+lh.
    const int src = 2 * l31 + lh;
    union { unsigned u[4]; bf16x8 v; } sf;
    sf.u[0] = __shfl((int)sp0, src);
    sf.u[1] = __shfl((int)sp1, src);
    sf.u[2] = __shfl((int)sp2, src);
    sf.u[3] = __shfl((int)sp3, src);
    const bf16x8 sfrag = sf.v;

    // ---------------- Phase 2: GEMM1 + GELU -> h in registers ----------------
    // D1[i=n][j=m] per tile nt. Lane reg r: n = 32nt + (r&3)+8*(r>>2)+4*lh.
    // Repack into GEMM2 B-frag layout (k = s*16 + lh*8 + j) via shfl_xor(32):
    //   frag(s=2*st+t): lh0 -> [own chunk(2t), partner chunk(2t)]
    //                   lh1 -> [partner chunk(2t+1), own chunk(2t+1)]
    unsigned hreg[64];
    #pragma unroll
    for (int nt = 0; nt < 8; ++nt) {
        union { unsigned u[4]; bf16x8 v; } wf;
        *(uint4*)wf.u = *(const uint4*)&w1f[(size_t)(nt * 64 + lane) * 8];
        f32x16 c;
        #pragma unroll
        for (int g = 0; g < 4; ++g) {
            float4 bv = *(const float4*)&b1[nt * 32 + 8 * g + 4 * lh];
            c[4*g+0] = bv.x; c[4*g+1] = bv.y; c[4*g+2] = bv.z; c[4*g+3] = bv.w;
        }
        c = __builtin_amdgcn_mfma_f32_32x32x16_bf16(wf.v, sfrag, c, 0, 0, 0);
        unsigned own[8], rcv[8];
        #pragma unroll
        for (int g = 0; g < 4; ++g) {
            own[2*g+0] = pk2(gelu_f(c[4*g+0]), gelu_f(c[4*g+1]));
            own[2*g+1] = pk2(gelu_f(c[4*g+2]), gelu_f(c[4*g+3]));
        }
        #pragma unroll
        for (int j = 0; j < 8; ++j) rcv[j] = (unsigned)__shfl_xor((int)own[j], 32);
        #pragma unroll
        for (int t = 0; t < 2; ++t) {
            const int b = nt * 8 + t * 4;
            hreg[b+0] = lh ? rcv[4*t+2] : own[4*t+0];
            hreg[b+1] = lh ? rcv[4*t+3] : own[4*t+1];
            hreg[b+2] = lh ? own[4*t+2] : rcv[4*t+0];
            hreg[b+3] = lh ? own[4*t+3] : rcv[4*t+1];
        }
    }

    // ---------------- Phase 3: GEMM2 from registers -> out ----------------
    #pragma unroll
    for (int nt = 0; nt < 8; ++nt) {
        f32x16 acc;
        #pragma unroll
        for (int g = 0; g < 4; ++g) {
            float4 bv = *(const float4*)&b2[nt * 32 + 8 * g + 4 * lh];
            acc[4*g+0] = bv.x; acc[4*g+1] = bv.y;
            acc[4*g+2] = bv.z; acc[4*g+3] = bv.w;
        }
        #pragma unroll
        for (int s = 0; s < 16; ++s) {
            union { unsigned u[4]; bf16x8 v; } wf;
            *(uint4*)wf.u = *(const uint4*)&w2f[(size_t)((s * 8 + nt) * 64 + lane) * 8];
            union { unsigned u[4]; bf16x8 v; } bf;
            const int b = (s >> 1) * 8 + (s & 1) * 4;
            bf.u[0] = hreg[b+0]; bf.u[1] = hreg[b+1];
            bf.u[2] = hreg[b+2]; bf.u[3] = hreg[b+3];
            acc = __builtin_amdgcn_mfma_f32_32x32x16_bf16(wf.v, bf.v, acc, 0, 0, 0);
        }
        #pragma unroll
        for (int g = 0; g < 4; ++g) {
            float4 o;
            o.x = acc[4*g+0]; o.y = acc[4*g+1];
            o.z = acc[4*g+2]; o.w = acc[4*g+3];
            *(float4*)&out[(size_t)(rbase + l31) * DD + nt * 32 + 8 * g + 4 * lh] = o;
        }
    }
}

extern "C" void kernel_launch(void* const* d_in, const int* in_sizes, int n_in,
                              void* d_out, int out_size, void* d_ws, size_t ws_size,
                              hipStream_t stream) {
    const int*   y  = (const int*)d_in[0];
    const float* w1 = (const float*)d_in[1];
    const float* b1 = (const float*)d_in[2];
    const float* w2 = (const float*)d_in[3];
    const float* b2 = (const float*)d_in[4];
    float* out = (float*)d_out;

    unsigned short* w2f = (unsigned short*)d_ws;        // 65536 shorts (128 KB)
    unsigned short* w1f = w2f + 65536;                  // 4096 shorts (8 KB)

    prep_kernel<<<34, 256, 0, stream>>>(w1, w2, w1f, w2f);

    const int nrows = in_sizes[0] / SSUP;               // 65536
    encoder_kernel<<<nrows / 128, 256, 0, stream>>>(y, b1, b2, w1f, w2f, out);
}

// Round 5
// 135.800 us; speedup vs baseline: 1.0771x; 1.0771x over previous
//
#include <hip/hip_runtime.h>
#include <hip/hip_bf16.h>
#include <stdint.h>

// TargetTokenEncoder: histogram-stats -> MLP(14->256 GELU ->256) fused.
// R5: R4's zero-LDS wave-independent design, fixed resource contract:
// __launch_bounds__(256,2) (256-VGPR budget -> hreg[64] stays in registers,
// no scratch spill), v_cvt_pk_bf16_f32 packing, leaner GELU.

#define SSUP 128
#define DD   256

typedef __attribute__((ext_vector_type(8)))  short bf16x8;   // 8 bf16 = 4 VGPRs
typedef __attribute__((ext_vector_type(16))) float f32x16;   // C/D for 32x32 MFMA

__device__ __forceinline__ unsigned f2bf_u(float f) {
    union { float f; unsigned u; } v; v.f = f;
    return (v.u + 0x7FFFu + ((v.u >> 16) & 1u)) >> 16;   // RNE, no NaNs here
}
__device__ __forceinline__ unsigned pk2(float a, float b) {
    return f2bf_u(a) | (f2bf_u(b) << 16);
}
// Fast packed bf16 pair (v_cvt_pk_bf16_f32 on gfx950), RNE.
__device__ __forceinline__ unsigned pk2f(float a, float b) {
    union { __hip_bfloat162 h; unsigned u; } cv;
    cv.h = __float22bfloat162_rn(make_float2(a, b));
    return cv.u;
}

// tanh-form GELU: gelu(x) = x / (1 + exp(x*(A + B x^2))), A=-2a, B=-2ab.
// |dev from exact erf-GELU| < 0.003 << tolerance. Saturates correctly.
__device__ __forceinline__ float gelu_f(float x) {
    float t = x * x;
    float u = __builtin_fmaf(t, -0.0713548162726f, -1.5957691216057f);
    float e = __expf(x * u);
    return x * __builtin_amdgcn_rcpf(1.0f + e);
}

// Fragment-major weights (A-operand: i = n = 32nt + (l&31), k = (l>>5)*8+j):
//   w2f[((s*8 + nt)*64 + l)*8 + j] = bf16(w2[(s*16 + (l>>5)*8 + j)*256 + n])
//   w1f[(nt*64 + l)*8 + j]         = bf16(w1[((l>>5)*8+j)*256 + n]), pad k>=14
__global__ void prep_kernel(const float* __restrict__ w1,
                            const float* __restrict__ w2,
                            unsigned short* __restrict__ w1f,
                            unsigned short* __restrict__ w2f) {
    int tid = blockIdx.x * 256 + threadIdx.x;
    if (tid < 8192) {                       // w2f: one thread per (s,nt,lane)
        int l  = tid & 63;
        int nt = (tid >> 6) & 7;
        int s  = tid >> 9;
        int n  = nt * 32 + (l & 31);
        int k0 = s * 16 + (l >> 5) * 8;
        unsigned pk[4];
        #pragma unroll
        for (int h = 0; h < 4; ++h)
            pk[h] = pk2(w2[(size_t)(k0 + 2*h) * DD + n],
                        w2[(size_t)(k0 + 2*h + 1) * DD + n]);
        *(uint4*)&w2f[(size_t)tid * 8] = make_uint4(pk[0], pk[1], pk[2], pk[3]);
    } else if (tid < 8704) {                // w1f
        int idx = tid - 8192;
        int l   = idx & 63;
        int nt  = idx >> 6;
        int n   = nt * 32 + (l & 31);
        int kk0 = (l >> 5) * 8;
        unsigned pk[4];
        #pragma unroll
        for (int h = 0; h < 4; ++h) {
            int ka = kk0 + 2*h, kb = kk0 + 2*h + 1;
            float fa = (ka < 14) ? w1[(size_t)ka * DD + n] : 0.0f;
            float fb = (kb < 14) ? w1[(size_t)kb * DD + n] : 0.0f;
            pk[h] = pk2(fa, fb);
        }
        *(uint4*)&w1f[(size_t)idx * 8] = make_uint4(pk[0], pk[1], pk[2], pk[3]);
    }
}

__global__ __launch_bounds__(256, 2)
void encoder_kernel(const int* __restrict__ y,
                    const float* __restrict__ b1,
                    const float* __restrict__ b2,
                    const unsigned short* __restrict__ w1f,
                    const unsigned short* __restrict__ w2f,
                    float* __restrict__ out) {
    const int tid  = threadIdx.x;
    const int lane = tid & 63;
    const int wid  = tid >> 6;
    const int l31  = lane & 31;
    const int lh   = lane >> 5;
    const int rbase = blockIdx.x * 128 + wid * 32;   // 32 rows per wave

    // ---------------- Phase 1: in-wave histogram (2 lanes/row) ----------------
    // Each lane: 64 labels in two 32-label groups, 10 counters 6-bit-packed.
    const int hrow = lane >> 1;
    const int hq   = lane & 1;
    const int4* yp = (const int4*)(y + (size_t)(rbase + hrow) * SSUP);
    unsigned long long pka = 0ull, pkb = 0ull;
    #pragma unroll
    for (int i = 0; i < 8; ++i) {
        int4 v = yp[2 * i + hq];
        pka += 1ull << (6 * v.x);
        pka += 1ull << (6 * v.y);
        pka += 1ull << (6 * v.z);
        pka += 1ull << (6 * v.w);
    }
    #pragma unroll
    for (int i = 8; i < 16; ++i) {
        int4 v = yp[2 * i + hq];
        pkb += 1ull << (6 * v.x);
        pkb += 1ull << (6 * v.y);
        pkb += 1ull << (6 * v.z);
        pkb += 1ull << (6 * v.w);
    }
    float p[10]; float ent = 0.f, pmax = 0.f, nnz = 0.f;
    #pragma unroll
    for (int c = 0; c < 10; ++c) {
        int cc = (int)((pka >> (6 * c)) & 63ull) + (int)((pkb >> (6 * c)) & 63ull);
        cc += __shfl_xor(cc, 1);                  // pair-reduce: both lanes get total
        float pc = (float)cc * 0.0078125f;        // total is always 128
        p[c] = pc;
        nnz += (cc > 0) ? 1.0f : 0.0f;
        ent -= pc * __logf(pc + 1e-6f);
        pmax = fmaxf(pmax, pc);
    }
    // Pack stats as bf16: even lane of pair holds k0..7, odd holds k8..15.
    unsigned sp0 = hq ? pk2f(p[8], p[9])     : pk2f(p[0], p[1]);
    unsigned sp1 = hq ? pk2f(nnz, ent)       : pk2f(p[2], p[3]);
    unsigned sp2 = hq ? pk2f(128.0f, pmax)   : pk2f(p[4], p[5]);
    unsigned sp3 = hq ? 0u                   : pk2f(p[6], p[7]);
    // Redistribute to B-frag layout: lane (m=l31, lh) reads from lane 2*m+lh.
    const int src = 2 * l31 + lh;
    union { unsigned u[4]; bf16x8 v; } sf;
    sf.u[0] = __shfl((int)sp0, src);
    sf.u[1] = __shfl((int)sp1, src);
    sf.u[2] = __shfl((int)sp2, src);
    sf.u[3] = __shfl((int)sp3, src);
    const bf16x8 sfrag = sf.v;

    // ---------------- Phase 2: GEMM1 + GELU -> h in registers ----------------
    // D1[i=n][j=m] per tile nt. Lane reg r: n = 32nt + (r&3)+8*(r>>2)+4*lh.
    // Repack into GEMM2 B-frag layout (k = s*16 + lh*8 + j) via shfl_xor(32).
    unsigned hreg[64];
    #pragma unroll
    for (int nt = 0; nt < 8; ++nt) {
        union { unsigned u[4]; bf16x8 v; } wf;
        *(uint4*)wf.u = *(const uint4*)&w1f[(size_t)(nt * 64 + lane) * 8];
        f32x16 c;
        #pragma unroll
        for (int g = 0; g < 4; ++g) {
            float4 bv = *(const float4*)&b1[nt * 32 + 8 * g + 4 * lh];
            c[4*g+0] = bv.x; c[4*g+1] = bv.y; c[4*g+2] = bv.z; c[4*g+3] = bv.w;
        }
        c = __builtin_amdgcn_mfma_f32_32x32x16_bf16(wf.v, sfrag, c, 0, 0, 0);
        unsigned own[8], rcv[8];
        #pragma unroll
        for (int g = 0; g < 4; ++g) {
            own[2*g+0] = pk2f(gelu_f(c[4*g+0]), gelu_f(c[4*g+1]));
            own[2*g+1] = pk2f(gelu_f(c[4*g+2]), gelu_f(c[4*g+3]));
        }
        #pragma unroll
        for (int j = 0; j < 8; ++j) rcv[j] = (unsigned)__shfl_xor((int)own[j], 32);
        #pragma unroll
        for (int t = 0; t < 2; ++t) {
            const int b = nt * 8 + t * 4;
            hreg[b+0] = lh ? rcv[4*t+2] : own[4*t+0];
            hreg[b+1] = lh ? rcv[4*t+3] : own[4*t+1];
            hreg[b+2] = lh ? own[4*t+2] : rcv[4*t+0];
            hreg[b+3] = lh ? own[4*t+3] : rcv[4*t+1];
        }
    }

    // ---------------- Phase 3: GEMM2 from registers -> out ----------------
    #pragma unroll
    for (int nt = 0; nt < 8; ++nt) {
        f32x16 acc;
        #pragma unroll
        for (int g = 0; g < 4; ++g) {
            float4 bv = *(const float4*)&b2[nt * 32 + 8 * g + 4 * lh];
            acc[4*g+0] = bv.x; acc[4*g+1] = bv.y;
            acc[4*g+2] = bv.z; acc[4*g+3] = bv.w;
        }
        #pragma unroll
        for (int s = 0; s < 16; ++s) {
            union { unsigned u[4]; bf16x8 v; } wf;
            *(uint4*)wf.u = *(const uint4*)&w2f[(size_t)((s * 8 + nt) * 64 + lane) * 8];
            union { unsigned u[4]; bf16x8 v; } bf;
            const int b = (s >> 1) * 8 + (s & 1) * 4;
            bf.u[0] = hreg[b+0]; bf.u[1] = hreg[b+1];
            bf.u[2] = hreg[b+2]; bf.u[3] = hreg[b+3];
            acc = __builtin_amdgcn_mfma_f32_32x32x16_bf16(wf.v, bf.v, acc, 0, 0, 0);
        }
        #pragma unroll
        for (int g = 0; g < 4; ++g) {
            float4 o;
            o.x = acc[4*g+0]; o.y = acc[4*g+1];
            o.z = acc[4*g+2]; o.w = acc[4*g+3];
            *(float4*)&out[(size_t)(rbase + l31) * DD + nt * 32 + 8 * g + 4 * lh] = o;
        }
    }
}

extern "C" void kernel_launch(void* const* d_in, const int* in_sizes, int n_in,
                              void* d_out, int out_size, void* d_ws, size_t ws_size,
                              hipStream_t stream) {
    const int*   y  = (const int*)d_in[0];
    const float* w1 = (const float*)d_in[1];
    const float* b1 = (const float*)d_in[2];
    const float* w2 = (const float*)d_in[3];
    const float* b2 = (const float*)d_in[4];
    float* out = (float*)d_out;

    unsigned short* w2f = (unsigned short*)d_ws;        // 65536 shorts (128 KB)
    unsigned short* w1f = w2f + 65536;                  // 4096 shorts (8 KB)

    prep_kernel<<<34, 256, 0, stream>>>(w1, w2, w1f, w2f);

    const int nrows = in_sizes[0] / SSUP;               // 65536
    encoder_kernel<<<nrows / 128, 256, 0, stream>>>(y, b1, b2, w1f, w2f, out);
}

// Round 6
// 112.073 us; speedup vs baseline: 1.3051x; 1.2117x over previous
//
#include <hip/hip_runtime.h>
#include <hip/hip_bf16.h>
#include <stdint.h>

// TargetTokenEncoder: histogram-stats -> MLP(14->256 GELU ->256) fused.
// R6: max-occupancy small blocks. 32 rows / 256 threads / ~17KB LDS ->
// 8 blocks/CU = 32 waves/CU. Hist split 8 lanes/row over all waves; h is
// repacked in-register (shfl_xor 32) into GEMM2 B-frag layout and staged in
// LDS fragment-major (conflict-free b128 write/read). Phase 3: 16 short
// steps, acc[2] (32 regs) -> fits (256,8) without spill.

#define SSUP 128
#define DD   256

typedef __attribute__((ext_vector_type(8)))  short bf16x8;   // 8 bf16 = 4 VGPRs
typedef __attribute__((ext_vector_type(16))) float f32x16;   // C/D for 32x32 MFMA

__device__ __forceinline__ unsigned f2bf_u(float f) {
    union { float f; unsigned u; } v; v.f = f;
    return (v.u + 0x7FFFu + ((v.u >> 16) & 1u)) >> 16;   // RNE, no NaNs here
}
__device__ __forceinline__ unsigned pk2(float a, float b) {
    return f2bf_u(a) | (f2bf_u(b) << 16);
}
// Fast packed bf16 pair (v_cvt_pk_bf16_f32 on gfx950), RNE.
__device__ __forceinline__ unsigned pk2f(float a, float b) {
    union { __hip_bfloat162 h; unsigned u; } cv;
    cv.h = __float22bfloat162_rn(make_float2(a, b));
    return cv.u;
}

// tanh-form GELU: gelu(x) = x / (1 + exp(x*(A + B x^2))).
// |dev from exact erf-GELU| < 0.003 << tolerance. Saturates correctly.
__device__ __forceinline__ float gelu_f(float x) {
    float t = x * x;
    float u = __builtin_fmaf(t, -0.0713548162726f, -1.5957691216057f);
    float e = __expf(x * u);
    return x * __builtin_amdgcn_rcpf(1.0f + e);
}

// Fragment-major weights (A-operand: i = n = 32nt + (l&31), k = (l>>5)*8+j):
//   w2f[((s*8 + nt)*64 + l)*8 + j] = bf16(w2[(s*16 + (l>>5)*8 + j)*256 + n])
//   w1f[(nt*64 + l)*8 + j]         = bf16(w1[((l>>5)*8+j)*256 + n]), pad k>=14
__global__ void prep_kernel(const float* __restrict__ w1,
                            const float* __restrict__ w2,
                            unsigned short* __restrict__ w1f,
                            unsigned short* __restrict__ w2f) {
    int tid = blockIdx.x * 256 + threadIdx.x;
    if (tid < 8192) {                       // w2f: one thread per (s,nt,lane)
        int l  = tid & 63;
        int nt = (tid >> 6) & 7;
        int s  = tid >> 9;
        int n  = nt * 32 + (l & 31);
        int k0 = s * 16 + (l >> 5) * 8;
        unsigned pk[4];
        #pragma unroll
        for (int h = 0; h < 4; ++h)
            pk[h] = pk2(w2[(size_t)(k0 + 2*h) * DD + n],
                        w2[(size_t)(k0 + 2*h + 1) * DD + n]);
        *(uint4*)&w2f[(size_t)tid * 8] = make_uint4(pk[0], pk[1], pk[2], pk[3]);
    } else if (tid < 8704) {                // w1f
        int idx = tid - 8192;
        int l   = idx & 63;
        int nt  = idx >> 6;
        int n   = nt * 32 + (l & 31);
        int kk0 = (l >> 5) * 8;
        unsigned pk[4];
        #pragma unroll
        for (int h = 0; h < 4; ++h) {
            int ka = kk0 + 2*h, kb = kk0 + 2*h + 1;
            float fa = (ka < 14) ? w1[(size_t)ka * DD + n] : 0.0f;
            float fb = (kb < 14) ? w1[(size_t)kb * DD + n] : 0.0f;
            pk[h] = pk2(fa, fb);
        }
        *(uint4*)&w1f[(size_t)idx * 8] = make_uint4(pk[0], pk[1], pk[2], pk[3]);
    }
}

__global__ __launch_bounds__(256, 8)
void encoder_kernel(const int* __restrict__ y,
                    const float* __restrict__ b1,
                    const float* __restrict__ b2,
                    const unsigned short* __restrict__ w1f,
                    const unsigned short* __restrict__ w2f,
                    float* __restrict__ out) {
    // stats_lds[row*2+half]: 4 packed u32 = 8 bf16 of the stats vector half.
    __shared__ __align__(16) unsigned stats_lds[64][4];            // 1 KB
    // hb[((s*2+lh)*32+m)*8 ..+7]: GEMM2 B-frag data, fragment-major.
    __shared__ __align__(16) unsigned short hb[16 * 2 * 32 * 8];   // 16 KB

    const int tid  = threadIdx.x;
    const int lane = tid & 63;
    const int wid  = tid >> 6;   // 0..3 = N-quarter owner
    const int l31  = lane & 31;
    const int lh   = lane >> 5;
    const int rbase = blockIdx.x * 32;

    // ---------------- Phase 1: histogram, 8 lanes/row over all waves --------
    const int hrow = wid * 8 + (lane >> 3);   // 0..31
    const int sub  = lane & 7;
    const int4* yp = (const int4*)(y + (size_t)(rbase + hrow) * SSUP);
    unsigned long long pk = 0ull;             // 10 counters, 6-bit packed
    #pragma unroll
    for (int i = 0; i < 4; ++i) {
        int4 v = yp[i * 8 + sub];             // 8-lane group: 128B contiguous
        pk += 1ull << (6 * v.x);
        pk += 1ull << (6 * v.y);
        pk += 1ull << (6 * v.z);
        pk += 1ull << (6 * v.w);
    }
    pk += __shfl_xor((long long)pk, 1);       // per-class <=32, still fits 6b
    float p[10]; float ent = 0.f, pmax = 0.f, nnz = 0.f;
    #pragma unroll
    for (int c = 0; c < 10; ++c) {
        int cc = (int)((pk >> (6 * c)) & 63ull);
        cc += __shfl_xor(cc, 2);
        cc += __shfl_xor(cc, 4);              // full row total (<=128) in 32b
        float pc = (float)cc * 0.0078125f;    // total is always 128
        p[c] = pc;
        nnz += (cc > 0) ? 1.0f : 0.0f;
        ent -= pc * __logf(pc + 1e-6f);
        pmax = fmaxf(pmax, pc);
    }
    if (sub < 2) {
        uint4 st;
        if (sub == 0) st = make_uint4(pk2f(p[0], p[1]), pk2f(p[2], p[3]),
                                      pk2f(p[4], p[5]), pk2f(p[6], p[7]));
        else          st = make_uint4(pk2f(p[8], p[9]), pk2f(nnz, ent),
                                      pk2f(128.0f, pmax), 0u);
        *(uint4*)&stats_lds[hrow * 2 + sub][0] = st;
    }
    __syncthreads();

    // Stats B-frag: lane (m=l31, lh) takes half lh of row m's stats.
    union { unsigned u[4]; bf16x8 v; } sf;
    *(uint4*)sf.u = *(const uint4*)&stats_lds[l31 * 2 + lh][0];
    const bf16x8 sfrag = sf.v;

    // ---------------- Phase 2: GEMM1 + GELU -> B-frag-ready h in LDS --------
    // D1[i=n][j=m] per tile nt (wave owns nt = 2wid, 2wid+1). Repack lane's
    // 16 outputs into GEMM2 B-frag chunks via shfl_xor(32), write b128.
    #pragma unroll
    for (int t = 0; t < 2; ++t) {
        const int nt = wid * 2 + t;
        union { unsigned u[4]; bf16x8 v; } wf;
        *(uint4*)wf.u = *(const uint4*)&w1f[(size_t)(nt * 64 + lane) * 8];
        f32x16 c;
        #pragma unroll
        for (int g = 0; g < 4; ++g) {
            float4 bv = *(const float4*)&b1[nt * 32 + 8 * g + 4 * lh];
            c[4*g+0] = bv.x; c[4*g+1] = bv.y; c[4*g+2] = bv.z; c[4*g+3] = bv.w;
        }
        c = __builtin_amdgcn_mfma_f32_32x32x16_bf16(wf.v, sfrag, c, 0, 0, 0);
        unsigned own[8], rcv[8];
        #pragma unroll
        for (int g = 0; g < 4; ++g) {
            own[2*g+0] = pk2f(gelu_f(c[4*g+0]), gelu_f(c[4*g+1]));
            own[2*g+1] = pk2f(gelu_f(c[4*g+2]), gelu_f(c[4*g+3]));
        }
        #pragma unroll
        for (int j = 0; j < 8; ++j) rcv[j] = (unsigned)__shfl_xor((int)own[j], 32);
        #pragma unroll
        for (int tt = 0; tt < 2; ++tt) {
            const int s = 2 * nt + tt;
            uint4 fr;
            fr.x = lh ? rcv[4*tt+2] : own[4*tt+0];
            fr.y = lh ? rcv[4*tt+3] : own[4*tt+1];
            fr.z = lh ? own[4*tt+2] : rcv[4*tt+0];
            fr.w = lh ? own[4*tt+3] : rcv[4*tt+1];
            *(uint4*)&hb[(size_t)((s * 2 + lh) * 32 + l31) * 8] = fr;
        }
    }
    __syncthreads();

    // ---------------- Phase 3: GEMM2 -> out ----------------
    f32x16 acc[2];
    #pragma unroll
    for (int u = 0; u < 2; ++u) {
        const int nt = wid * 2 + u;
        #pragma unroll
        for (int g = 0; g < 4; ++g) {
            float4 bv = *(const float4*)&b2[nt * 32 + 8 * g + 4 * lh];
            acc[u][4*g+0] = bv.x; acc[u][4*g+1] = bv.y;
            acc[u][4*g+2] = bv.z; acc[u][4*g+3] = bv.w;
        }
    }
    #pragma unroll
    for (int s = 0; s < 16; ++s) {
        union { unsigned u[4]; bf16x8 v; } hf;
        *(uint4*)hf.u = *(const uint4*)&hb[(size_t)((s * 2 + lh) * 32 + l31) * 8];
        #pragma unroll
        for (int u = 0; u < 2; ++u) {
            const int nt = wid * 2 + u;
            union { unsigned u[4]; bf16x8 v; } wf;
            *(uint4*)wf.u = *(const uint4*)&w2f[(size_t)((s * 8 + nt) * 64 + lane) * 8];
            acc[u] = __builtin_amdgcn_mfma_f32_32x32x16_bf16(wf.v, hf.v, acc[u], 0, 0, 0);
        }
    }
    #pragma unroll
    for (int u = 0; u < 2; ++u) {
        const int nt = wid * 2 + u;
        #pragma unroll
        for (int g = 0; g < 4; ++g) {
            float4 o;
            o.x = acc[u][4*g+0]; o.y = acc[u][4*g+1];
            o.z = acc[u][4*g+2]; o.w = acc[u][4*g+3];
            *(float4*)&out[(size_t)(rbase + l31) * DD + nt * 32 + 8 * g + 4 * lh] = o;
        }
    }
}

extern "C" void kernel_launch(void* const* d_in, const int* in_sizes, int n_in,
                              void* d_out, int out_size, void* d_ws, size_t ws_size,
                              hipStream_t stream) {
    const int*   y  = (const int*)d_in[0];
    const float* w1 = (const float*)d_in[1];
    const float* b1 = (const float*)d_in[2];
    const float* w2 = (const float*)d_in[3];
    const float* b2 = (const float*)d_in[4];
    float* out = (float*)d_out;

    unsigned short* w2f = (unsigned short*)d_ws;        // 65536 shorts (128 KB)
    unsigned short* w1f = w2f + 65536;                  // 4096 shorts (8 KB)

    prep_kernel<<<34, 256, 0, stream>>>(w1, w2, w1f, w2f);

    const int nrows = in_sizes[0] / SSUP;               // 65536
    encoder_kernel<<<nrows / 32, 256, 0, stream>>>(y, b1, b2, w1f, w2f, out);
}